// Round 13
// baseline (360.625 us; speedup 1.0000x reference)
//
#include <hip/hip_runtime.h>
#include <hip/hip_bf16.h>

#define BB  32
#define TXX 2048
#define DHH 512
#define UU  1024
#define MM  (BB*TXX)   // 65536

typedef __attribute__((ext_vector_type(8))) short s8v;
typedef __attribute__((ext_vector_type(4))) float f4v;

#define GLDS16(g, l)                                                        \
  __builtin_amdgcn_global_load_lds(                                         \
      (const __attribute__((address_space(1))) void*)(g),                   \
      (__attribute__((address_space(3))) void*)(l), 16, 0, 0)

__device__ __forceinline__ ushort f2bf(float f) {
  return __builtin_bit_cast(ushort, __float2bfloat16(f));
}
__device__ __forceinline__ float bf2f(ushort u) {
  unsigned x = ((unsigned)u) << 16;
  return __builtin_bit_cast(float, x);
}

__device__ __forceinline__ float tanh_fast(float x) {
  float ax = fabsf(x);
  float e2 = __expf(-2.0f * ax);
  float t = (1.0f - e2) * __builtin_amdgcn_rcpf(1.0f + e2);
  return copysignf(t, x);
}

// LDS unit index for the reg-staging fallback kernel.
__device__ __forceinline__ int ldsu(int frag, int kh, int i15) {
  return (frag << 6) | (kh << 4) | (i15 ^ (kh << 2));
}

// ---------------------------------------------------------------------------
// PREP (fused, fast path): blockIdx-partitioned independent preprocessing.
// ---------------------------------------------------------------------------
#define PREP_A2BF   32768
#define PREP_WT     256
#define PREP_DEC    128
#define PREP_GRID   (PREP_A2BF + PREP_WT + PREP_DEC)

__global__ __launch_bounds__(256) void prep_kernel(
    const float* __restrict__ a, ushort* __restrict__ abf,
    const float* __restrict__ Wa, ushort* __restrict__ WaT,
    const float* __restrict__ h, const float* __restrict__ Whw,
    const float* __restrict__ Whb, float* __restrict__ dec) {
  __shared__ float Ts[64][65];
  const int bid = blockIdx.x;
  const int tid = threadIdx.x;

  if (bid < PREP_A2BF) {
    const size_t i = ((size_t)bid * 256 + tid) * 8;
    float4 v0 = *(const float4*)(a + i);
    float4 v1 = *(const float4*)(a + i + 4);
    ushort u[8] = {f2bf(v0.x), f2bf(v0.y), f2bf(v0.z), f2bf(v0.w),
                   f2bf(v1.x), f2bf(v1.y), f2bf(v1.z), f2bf(v1.w)};
    *(uint4*)(abf + i) = *(const uint4*)u;
  } else if (bid < PREP_A2BF + PREP_WT) {
    const int wb = bid - PREP_A2BF;
    const int jb = wb & 15, kb = wb >> 4;
    const int c = tid & 63, r0 = tid >> 6;
#pragma unroll
    for (int i = 0; i < 16; ++i) {
      int kl = r0 + 4 * i;
      Ts[c][kl] = Wa[(size_t)(kb * 64 + kl) * UU + jb * 64 + c];
    }
    __syncthreads();
#pragma unroll
    for (int i = 0; i < 16; ++i) {
      int jl = r0 + 4 * i;
      WaT[(size_t)(jb * 64 + jl) * UU + kb * 64 + c] = f2bf(Ts[jl][c]);
    }
  } else {
    const int db = bid - PREP_A2BF - PREP_WT;
    const int b = db >> 2, c = db & 3;
    float* hs = &Ts[0][0];
    for (int k = tid; k < DHH; k += 256) hs[k] = h[b * DHH + k];
    __syncthreads();
    const int j = c * 256 + tid;
    float acc = Whb[j];
#pragma unroll 8
    for (int k = 0; k < DHH; ++k) acc = fmaf(hs[k], Whw[(size_t)k * UU + j], acc);
    dec[b * UU + j] = acc;
  }
}

// Standalone copies for the ws-constrained fallback path.
__global__ __launch_bounds__(256) void watrans_kernel(
    const float* __restrict__ Wa, ushort* __restrict__ WaT) {
  __shared__ float Ts[64][65];
  const int jb = blockIdx.x & 15, kb = blockIdx.x >> 4;
  const int c = threadIdx.x & 63, r0 = threadIdx.x >> 6;
#pragma unroll
  for (int i = 0; i < 16; ++i) {
    int kl = r0 + 4 * i;
    Ts[c][kl] = Wa[(size_t)(kb * 64 + kl) * UU + jb * 64 + c];
  }
  __syncthreads();
#pragma unroll
  for (int i = 0; i < 16; ++i) {
    int jl = r0 + 4 * i;
    WaT[(size_t)(jb * 64 + jl) * UU + kb * 64 + c] = f2bf(Ts[jl][c]);
  }
}

__global__ __launch_bounds__(256) void dec_kernel(
    const float* __restrict__ h, const float* __restrict__ Whw,
    const float* __restrict__ Whb, float* __restrict__ dec) {
  const int b = blockIdx.x >> 2, c = blockIdx.x & 3;
  __shared__ float hs[DHH];
  for (int k = threadIdx.x; k < DHH; k += 256) hs[k] = h[b * DHH + k];
  __syncthreads();
  const int j = c * 256 + threadIdx.x;
  float acc = Whb[j];
#pragma unroll 8
  for (int k = 0; k < DHH; ++k) acc = fmaf(hs[k], Whw[(size_t)k * UU + j], acc);
  dec[b * UU + j] = acc;
}

// ---------------------------------------------------------------------------
// K2: 256x256 tile, BK=64, 8 waves (2x4) — r8 structure, depth-3 staging,
// STAGES ISSUED AFTER THE BARRIER (r12 bug: stage before barrier -> WAR race
// with other waves' p2/p3(t-1) reads; absmax 3.3e-3 corruption).
//
// Ring of 4 half-buffers per operand (2 slots x 2 kf). Per tile t:
//   p0: VMBAR(G0) -> stage kf1(t+1) into slot (t+1)&1   (after barrier!)
//   p2: VMBAR(G1) -> stage kf0(t+2) into slot  t   &1   (after barrier!)
// Each half staged 6 phases before first consumption; 12 loads in flight.
//
// WAR safety (r8 argument): a buffer's last readers consumed their data
// (ds_read -> lgkm wait -> MFMA) before reaching the barrier that precedes
// the overwriting stage; sched_barrier(0) pins stages below the barrier.
//
// vmcnt ledger (4 loads per half-stage per thread, issue order
// ...kf0(t)@p2(t-2), kf1(t)@p0(t-1), kf0(t+1)@p2(t-1), kf1(t+1)@p0(t)...):
//   G0(t) needs kf0(t): younger = kf1(t),kf0(t+1) = 8 -> vmcnt(8)
//   G1(t) needs kf1(t): younger = kf0(t+1),kf1(t+1) = 8 -> vmcnt(8)
//   t=15: G0: younger = kf1(15) = 4; G1: 0.
// RAW: VMBAR = own-vmcnt wait THEN barrier -> all waves' loads landed.
// ---------------------------------------------------------------------------
__global__ __launch_bounds__(512, 1) void e_mfma8_kernel(
    const ushort* __restrict__ abf, const ushort* __restrict__ WaT,
    const float* __restrict__ dec, const float* __restrict__ cov,
    const float* __restrict__ Wc, const float* __restrict__ v,
    const int* __restrict__ use_cov_p, float* __restrict__ partial) {
  __shared__ __align__(16) ushort aS[32768];  // 2 slots x 2 kf x 8 KB
  __shared__ __align__(16) ushort bS[32768];
  __shared__ float dec_s[256], v_s[256], wc_s[256], cov_s[256];
  __shared__ float peL[4][256];

  const int tid = threadIdx.x;
  const int lane = tid & 63;
  const int w = tid >> 6;            // 0..7
  const int wm = w >> 2, wn = w & 3; // 2 x 4 waves

  // XCD swizzle: 4 consecutive blocks within an XCD = 4 nt of one mt.
  const int x = blockIdx.x & 7;
  const int r = blockIdx.x >> 3;     // 0..127
  const int nt = r & 3;
  const int mt = (r >> 2) * 8 + x;   // 0..255

  const int j0 = nt * 256;
  const int row0 = mt * 256;
  const int b = row0 >> 11;
  const int trow0 = row0 & (TXX - 1);

  if (tid < 256) {
    dec_s[tid] = dec[b * UU + j0 + tid];
    v_s[tid] = v[j0 + tid];
    wc_s[tid] = Wc[j0 + tid];
    cov_s[tid] = (*use_cov_p) ? cov[b * TXX + trow0 + tid] : 0.0f;
  }

  f4v acc[8][4];
#pragma unroll
  for (int mi = 0; mi < 8; ++mi)
#pragma unroll
    for (int ni = 0; ni < 4; ++ni) acc[mi][ni] = (f4v){0.f, 0.f, 0.f, 0.f};

  const ushort* __restrict__ aT = abf + (size_t)row0 * UU;
  const ushort* __restrict__ bT = WaT + (size_t)j0 * UU;
  const int i15 = lane & 15, khl = lane >> 4;

  auto stageA = [&](int kt, int ns, int kf) {
#pragma unroll
    for (int l = 0; l < 2; ++l) {
      const int frag = l * 8 + w;
      GLDS16(aT + (size_t)(frag * 16 + i15) * UU + kt * 64 + kf * 32 + khl * 8,
             &aS[ns * 16384 + kf * 8192 + (l * 512 + w * 64) * 8]);
    }
  };
  auto stageB = [&](int kt, int ns, int kf) {
#pragma unroll
    for (int l = 0; l < 2; ++l) {
      const int frag = l * 8 + w;
      GLDS16(bT + (size_t)(frag * 16 + i15) * UU + kt * 64 + kf * 32 + khl * 8,
             &bS[ns * 16384 + kf * 8192 + (l * 512 + w * 64) * 8]);
    }
  };
  auto readA = [&](s8v af[4], int slot, int kf, int mh) {
#pragma unroll
    for (int q = 0; q < 4; ++q) {
      const int frag = wm * 8 + mh * 4 + q;
      af[q] = *(const s8v*)&aS[slot * 16384 + kf * 8192 + frag * 512 + lane * 8];
    }
  };
  auto readB = [&](s8v bf[4], int slot, int kf) {
#pragma unroll
    for (int q = 0; q < 4; ++q) {
      const int frag = wn * 4 + q;
      bf[q] = *(const s8v*)&bS[slot * 16384 + kf * 8192 + frag * 512 + lane * 8];
    }
  };

#define MFMA16(MH)                                                          \
  do {                                                                      \
    __builtin_amdgcn_s_setprio(1);                                          \
    _Pragma("unroll")                                                       \
    for (int q = 0; q < 4; ++q)                                             \
      _Pragma("unroll")                                                     \
      for (int ni = 0; ni < 4; ++ni)                                        \
        acc[(MH)*4 + q][ni] = __builtin_amdgcn_mfma_f32_16x16x32_bf16(      \
            af[q], bf[ni], acc[(MH)*4 + q][ni], 0, 0, 0);                   \
    __builtin_amdgcn_s_setprio(0);                                          \
  } while (0)

#define VMBAR(N)                                                            \
  asm volatile("s_waitcnt vmcnt(" #N ")" ::: "memory");                     \
  __builtin_amdgcn_s_barrier();                                             \
  __builtin_amdgcn_sched_barrier(0)

// One K-tile; G0/G1 = vmcnt gates; S1 = stage kf1(t+1), S2 = stage kf0(t+2).
// Stages are issued AFTER the adjacent barrier (WAR-safe, see header).
#define TILE(T, G0, G1, S1, S2)                                             \
  do {                                                                      \
    const int slot = (T) & 1, nsl = slot ^ 1;                               \
    s8v af[4], bf[4];                                                       \
    VMBAR(G0);                                                              \
    if (S1) { stageA((T) + 1, nsl, 1); stageB((T) + 1, nsl, 1); }           \
    readB(bf, slot, 0);                                                     \
    readA(af, slot, 0, 0);                                                  \
    MFMA16(0);                                                              \
    readA(af, slot, 0, 1);                                                  \
    MFMA16(1);                                                              \
    VMBAR(G1);                                                              \
    if (S2) { stageA((T) + 2, slot, 0); stageB((T) + 2, slot, 0); }         \
    readB(bf, slot, 1);                                                     \
    readA(af, slot, 1, 0);                                                  \
    MFMA16(0);                                                              \
    readA(af, slot, 1, 1);                                                  \
    MFMA16(1);                                                              \
  } while (0)

  // prologue: kf0(0), kf1(0) -> slot0; kf0(1) -> slot1  (12 loads in flight)
  stageA(0, 0, 0); stageB(0, 0, 0);
  stageA(0, 0, 1); stageB(0, 0, 1);
  stageA(1, 1, 0); stageB(1, 1, 0);

  for (int t = 0; t < 14; ++t) TILE(t, 8, 8, 1, 1);
  TILE(14, 8, 8, 1, 0);   // no kf0(16)
  TILE(15, 4, 0, 0, 0);   // drain
#undef TILE
#undef VMBAR
#undef MFMA16

  // epilogue: f = acc + dec[j] + cov[m]*Wc[j]; pe += v[j]*tanh(f);
  // C/D map (m89/m91): col = lane&15, row = (lane>>4)*4 + reg.
  const int lj = lane & 15, lk = lane >> 4;
#pragma unroll
  for (int mi = 0; mi < 8; ++mi) {
#pragma unroll
    for (int r2 = 0; r2 < 4; ++r2) {
      const int rowl = wm * 128 + mi * 16 + lk * 4 + r2;
      const float cv = cov_s[rowl];
      float s = 0.f;
#pragma unroll
      for (int ni = 0; ni < 4; ++ni) {
        const int jl = wn * 64 + ni * 16 + lj;
        float f = acc[mi][ni][r2] + dec_s[jl] + cv * wc_s[jl];
        s += v_s[jl] * tanh_fast(f);
      }
      s += __shfl_xor(s, 1); s += __shfl_xor(s, 2);
      s += __shfl_xor(s, 4); s += __shfl_xor(s, 8);
      if (lj == 0) peL[wn][rowl] = s;
    }
  }
  __syncthreads();
  if (tid < 256)
    partial[(size_t)nt * MM + row0 + tid] =
        peL[0][tid] + peL[1][tid] + peL[2][tid] + peL[3][tid];
}

// ---------------------------------------------------------------------------
// K2 slow (fallback if ws too small): reg-staging kernel (round-3 proven).
// ---------------------------------------------------------------------------
__device__ __forceinline__ void e_epilogue8(
    f4v acc[4][4], const float* dec_s, const float* v_s, const float* wc_s,
    const float* cov_s, float peL[2][128], int lane, int wm, int wn,
    float* __restrict__ partial, int nt, int row0, int tid) {
  const int lj = lane & 15, lk = lane >> 4;
#pragma unroll
  for (int mi = 0; mi < 4; ++mi) {
#pragma unroll
    for (int r = 0; r < 4; ++r) {
      const int rowl = (wm << 6) + (mi << 4) + (lk << 2) + r;
      const float cv = cov_s[rowl];
      float s = 0.f;
#pragma unroll
      for (int ni = 0; ni < 4; ++ni) {
        const int jl = (wn << 6) + (ni << 4) + lj;
        float f = acc[mi][ni][r] + dec_s[jl] + cv * wc_s[jl];
        s += v_s[jl] * tanh_fast(f);
      }
      s += __shfl_xor(s, 1); s += __shfl_xor(s, 2);
      s += __shfl_xor(s, 4); s += __shfl_xor(s, 8);
      if (lj == 0) peL[wn][rowl] = s;
    }
  }
  __syncthreads();
  if (tid < 128)
    partial[(size_t)nt * MM + row0 + tid] = peL[0][tid] + peL[1][tid];
}

__global__ __launch_bounds__(256) void e_mfma_slow_kernel(
    const float* __restrict__ a, const ushort* __restrict__ WaT,
    const float* __restrict__ dec, const float* __restrict__ cov,
    const float* __restrict__ Wc, const float* __restrict__ v,
    const int* __restrict__ use_cov_p, float* __restrict__ partial) {
  __shared__ __align__(16) ushort aS[4096];
  __shared__ __align__(16) ushort bS[4096];
  __shared__ float dec_s[128], v_s[128], wc_s[128], cov_s[128];
  __shared__ float peL[2][128];

  const int tid = threadIdx.x;
  const int lane = tid & 63;
  const int wid = tid >> 6;
  const int wm = wid >> 1, wn = wid & 1;

  const int x = blockIdx.x & 7;
  const int q = blockIdx.x >> 3;
  const int nt = q & 7;
  const int mt = (q >> 3) * 8 + x;

  const int j0 = nt * 128;
  const int row0 = mt * 128;
  const int b = row0 >> 11;
  const int trow0 = row0 & (TXX - 1);

  if (tid < 128) {
    dec_s[tid] = dec[b * UU + j0 + tid];
    v_s[tid] = v[j0 + tid];
    wc_s[tid] = Wc[j0 + tid];
    cov_s[tid] = (*use_cov_p) ? cov[b * TXX + trow0 + tid] : 0.0f;
  }

  f4v zero = {0.f, 0.f, 0.f, 0.f};
  f4v acc[4][4];
#pragma unroll
  for (int mi = 0; mi < 4; ++mi)
#pragma unroll
    for (int ni = 0; ni < 4; ++ni) acc[mi][ni] = zero;

  const float* __restrict__ aRow = a + (size_t)row0 * UU;
  const int arow = tid >> 3;
  const int kq = (tid & 7) * 4;
  const int jrow = tid >> 2;
  const int kc = tid & 3;

  for (int ks = 0; ks < 32; ++ks) {
    const int k0 = ks * 32;
#pragma unroll
    for (int l = 0; l < 4; ++l) {
      const int row = l * 32 + arow;
      float4 va = *(const float4*)(aRow + (size_t)row * UU + k0 + kq);
      ushort4 ub = make_ushort4(f2bf(va.x), f2bf(va.y), f2bf(va.z), f2bf(va.w));
      const int unit = ldsu(row >> 4, kq >> 3, row & 15);
      *(ushort4*)&aS[unit * 8 + (kq & 7)] = ub;
    }
#pragma unroll
    for (int l = 0; l < 2; ++l) {
      const int jr = l * 64 + jrow;
      uint4 wv = *(const uint4*)(WaT + (size_t)(j0 + jr) * UU + k0 + kc * 8);
      *(uint4*)&bS[ldsu(jr >> 4, kc, jr & 15) * 8] = wv;
    }
    __syncthreads();
    s8v af[4], bff[4];
    const int kh = lane >> 4, i15 = lane & 15;
#pragma unroll
    for (int mi = 0; mi < 4; ++mi)
      af[mi] = *(const s8v*)&aS[ldsu((wm << 2) + mi, kh, i15) * 8];
#pragma unroll
    for (int ni = 0; ni < 4; ++ni)
      bff[ni] = *(const s8v*)&bS[ldsu((wn << 2) + ni, kh, i15) * 8];
#pragma unroll
    for (int mi = 0; mi < 4; ++mi)
#pragma unroll
      for (int ni = 0; ni < 4; ++ni)
        acc[mi][ni] = __builtin_amdgcn_mfma_f32_16x16x32_bf16(af[mi], bff[ni], acc[mi][ni], 0, 0, 0);
    __syncthreads();
  }

  e_epilogue8(acc, dec_s, v_s, wc_s, cov_s, peL, lane, wm, wn, partial, nt, row0, tid);
}

// ---------------------------------------------------------------------------
// K3: e = sum of npart partials; masked softmax over TX.
// ---------------------------------------------------------------------------
__global__ __launch_bounds__(256) void softmax_kernel(
    const float* __restrict__ partial, const void* __restrict__ mask,
    const int* __restrict__ use_mask_p, float* __restrict__ alpha, int npart) {
  int b = blockIdx.x;
  int tid = threadIdx.x;
  int lane = tid & 63, wv = tid >> 6;
  const unsigned char* m8 = (const unsigned char*)mask;
  const int* m32 = (const int*)mask;
  int um = *use_mask_p;

  __shared__ int isBoolS;
  if (tid == 0) isBoolS = 0;

  __shared__ float es[TXX];
  for (int t = tid; t < TXX; t += 256) {
    float s = 0.f;
    for (int nt = 0; nt < npart; ++nt) s += partial[(size_t)nt * MM + b * TXX + t];
    es[t] = s;
  }
  __syncthreads();
  {
    // int32-encoded 0/1 masks have all bytes at (i%4 != 0) == 0.
    uint4 qq = ((const uint4*)mask)[tid];
    unsigned nz = (qq.x | qq.y | qq.z | qq.w) & 0xFFFFFF00u;
    if (nz) atomicOr(&isBoolS, 1);
  }
  __syncthreads();
  const int isBool = isBoolS;

  float m = -1e30f;
  for (int t = tid; t < TXX; t += 256) m = fmaxf(m, es[t]);
#pragma unroll
  for (int o = 32; o > 0; o >>= 1) m = fmaxf(m, __shfl_xor(m, o, 64));
  __shared__ float redm[4];
  if (lane == 0) redm[wv] = m;
  __syncthreads();
  m = fmaxf(fmaxf(redm[0], redm[1]), fmaxf(redm[2], redm[3]));

  float s = 0.f;
  for (int t = tid; t < TXX; t += 256) {
    float w = __expf(es[t] - m);
    if (um) {
      int mv = isBool ? (int)m8[b * TXX + t] : m32[b * TXX + t];
      if (mv == 0) w = 0.f;
    }
    s += w;
  }
#pragma unroll
  for (int o = 32; o > 0; o >>= 1) s += __shfl_xor(s, o, 64);
  __shared__ float reds[4];
  if (lane == 0) reds[wv] = s;
  __syncthreads();
  s = reds[0] + reds[1] + reds[2] + reds[3];
  float inv = 1.0f / s;

  for (int t = tid; t < TXX; t += 256) {
    float w = __expf(es[t] - m);
    if (um) {
      int mv = isBool ? (int)m8[b * TXX + t] : m32[b * TXX + t];
      if (mv == 0) w = 0.f;
    }
    alpha[b * TXX + t] = w * inv;
  }
}

// ---------------------------------------------------------------------------
// K4 (bf16 input): cpart[ts][b][d] = sum_{t in chunk} alpha[b,t]*abf[b,t,d]
// ---------------------------------------------------------------------------
__global__ __launch_bounds__(256) void context_bf_kernel(
    const ushort* __restrict__ abf, const float* __restrict__ alpha,
    float* __restrict__ cpart) {
  const int b = blockIdx.x >> 4;
  const int ts = blockIdx.x & 15;
  const int th = threadIdx.x >> 7;
  const int c = threadIdx.x & 127;
  const int dc = c * 8;
  const ushort* __restrict__ ab = abf + (size_t)(b * TXX + ts * 128) * UU + dc;
  const float* __restrict__ alb = alpha + b * TXX + ts * 128;
  float acc[8] = {0.f, 0.f, 0.f, 0.f, 0.f, 0.f, 0.f, 0.f};
  for (int t = th; t < 128; t += 2) {
    float al = alb[t];
    union { uint4 q; ushort us[8]; } Q;
    Q.q = *(const uint4*)(ab + (size_t)t * UU);
#pragma unroll
    for (int u = 0; u < 8; ++u) acc[u] = fmaf(al, bf2f(Q.us[u]), acc[u]);
  }
  __shared__ float s2[2][128][8];
#pragma unroll
  for (int u = 0; u < 8; ++u) s2[th][c][u] = acc[u];
  __syncthreads();
  if (th == 0) {
    float o[8];
#pragma unroll
    for (int u = 0; u < 8; ++u) o[u] = s2[0][c][u] + s2[1][c][u];
    float* dst = cpart + (size_t)(ts * BB + b) * UU + dc;
    *(float4*)dst = make_float4(o[0], o[1], o[2], o[3]);
    *(float4*)(dst + 4) = make_float4(o[4], o[5], o[6], o[7]);
  }
}

// K4 fallback (f32 input), round-3 proven.
__global__ __launch_bounds__(256) void context_f32_kernel(
    const float* __restrict__ a, const float* __restrict__ alpha,
    float* __restrict__ cpart) {
  const int b = blockIdx.x >> 4;
  const int ts = blockIdx.x & 15;
  const int d4 = threadIdx.x * 4;
  const float* __restrict__ ab  = a + (size_t)(b * TXX + ts * 128) * UU;
  const float* __restrict__ alb = alpha + b * TXX + ts * 128;
  float4 acc = {0.f, 0.f, 0.f, 0.f};
  for (int t = 0; t < 128; t += 4) {
#pragma unroll
    for (int u = 0; u < 4; ++u) {
      float al = alb[t + u];
      float4 va = *(const float4*)(ab + (size_t)(t + u) * UU + d4);
      acc.x = fmaf(al, va.x, acc.x);
      acc.y = fmaf(al, va.y, acc.y);
      acc.z = fmaf(al, va.z, acc.z);
      acc.w = fmaf(al, va.w, acc.w);
    }
  }
  *(float4*)(cpart + (size_t)(ts * BB + b) * UU + d4) = acc;
}

// K5: ctx[b][d] = sum_ts cpart[ts][b][d]
__global__ __launch_bounds__(256) void ctx_reduce_kernel(
    const float* __restrict__ cpart, float* __restrict__ ctx) {
  int i = blockIdx.x * 256 + threadIdx.x;
  float s = 0.f;
#pragma unroll
  for (int ts = 0; ts < 16; ++ts) s += cpart[(size_t)ts * BB * UU + i];
  ctx[i] = s;
}

// ---------------------------------------------------------------------------
extern "C" void kernel_launch(void* const* d_in, const int* in_sizes, int n_in,
                              void* d_out, int out_size, void* d_ws, size_t ws_size,
                              hipStream_t stream) {
  const float* a   = (const float*)d_in[0];
  const float* h   = (const float*)d_in[1];
  const float* cov = (const float*)d_in[2];
  const void*  msk = d_in[3];
  const float* Wa  = (const float*)d_in[4];
  const float* Whw = (const float*)d_in[5];
  const float* Whb = (const float*)d_in[6];
  const float* Wc  = (const float*)d_in[7];
  const float* v   = (const float*)d_in[8];
  const int* use_cov  = (const int*)d_in[9];
  const int* use_mask = (const int*)d_in[10];

  float*  dec     = (float*)d_ws;                                  // 128 KB
  ushort* WaT     = (ushort*)((char*)d_ws + 131072);               // 2 MB
  float*  partial = (float*)((char*)d_ws + 131072 + 2097152);      // 2 MB
  float*  cpart   = partial;  // reuse: softmax consumes partial before K4
  ushort* abf     = (ushort*)((char*)d_ws + 4325376);              // 128 MB
  const size_t need = 4325376 + (size_t)MM * UU * 2;

  float* ctx   = (float*)d_out;
  float* alpha = (float*)d_out + BB * UU;

  if (ws_size >= need) {
    prep_kernel<<<PREP_GRID, 256, 0, stream>>>(a, abf, Wa, WaT, h, Whw, Whb, dec);
    e_mfma8_kernel<<<(MM / 256) * 4, 512, 0, stream>>>(abf, WaT, dec, cov, Wc, v, use_cov, partial);
    softmax_kernel<<<BB, 256, 0, stream>>>(partial, msk, use_mask, alpha, 4);
    context_bf_kernel<<<BB * 16, 256, 0, stream>>>(abf, alpha, cpart);
  } else {
    watrans_kernel<<<256, 256, 0, stream>>>(Wa, WaT);
    dec_kernel<<<BB * 4, 256, 0, stream>>>(h, Whw, Whb, dec);
    e_mfma_slow_kernel<<<(MM / 128) * 8, 256, 0, stream>>>(a, WaT, dec, cov, Wc, v, use_cov, partial);
    softmax_kernel<<<BB, 256, 0, stream>>>(partial, msk, use_mask, alpha, 8);
    context_f32_kernel<<<BB * 16, 256, 0, stream>>>(a, alpha, cpart);
  }
  ctx_reduce_kernel<<<BB * UU / 256, 256, 0, stream>>>(cpart, ctx);
}

// Round 14
// 308.724 us; speedup vs baseline: 1.1681x; 1.1681x over previous
//
#include <hip/hip_runtime.h>
#include <hip/hip_bf16.h>

#define BB  32
#define TXX 2048
#define DHH 512
#define UU  1024
#define MM  (BB*TXX)   // 65536

typedef __attribute__((ext_vector_type(8))) short s8v;
typedef __attribute__((ext_vector_type(4))) float f4v;

#define GLDS16(g, l)                                                        \
  __builtin_amdgcn_global_load_lds(                                         \
      (const __attribute__((address_space(1))) void*)(g),                   \
      (__attribute__((address_space(3))) void*)(l), 16, 0, 0)

__device__ __forceinline__ ushort f2bf(float f) {
  return __builtin_bit_cast(ushort, __float2bfloat16(f));
}
__device__ __forceinline__ float bf2f(ushort u) {
  unsigned x = ((unsigned)u) << 16;
  return __builtin_bit_cast(float, x);
}

__device__ __forceinline__ float tanh_fast(float x) {
  float ax = fabsf(x);
  float e2 = __expf(-2.0f * ax);
  float t = (1.0f - e2) * __builtin_amdgcn_rcpf(1.0f + e2);
  return copysignf(t, x);
}

// LDS unit index for the reg-staging fallback kernel.
__device__ __forceinline__ int ldsu(int frag, int kh, int i15) {
  return (frag << 6) | (kh << 4) | (i15 ^ (kh << 2));
}

// ---------------------------------------------------------------------------
// PREP (fused, fast path): blockIdx-partitioned independent preprocessing.
// ---------------------------------------------------------------------------
#define PREP_A2BF   32768
#define PREP_WT     256
#define PREP_DEC    128
#define PREP_GRID   (PREP_A2BF + PREP_WT + PREP_DEC)

__global__ __launch_bounds__(256) void prep_kernel(
    const float* __restrict__ a, ushort* __restrict__ abf,
    const float* __restrict__ Wa, ushort* __restrict__ WaT,
    const float* __restrict__ h, const float* __restrict__ Whw,
    const float* __restrict__ Whb, float* __restrict__ dec) {
  __shared__ float Ts[64][65];
  const int bid = blockIdx.x;
  const int tid = threadIdx.x;

  if (bid < PREP_A2BF) {
    const size_t i = ((size_t)bid * 256 + tid) * 8;
    float4 v0 = *(const float4*)(a + i);
    float4 v1 = *(const float4*)(a + i + 4);
    ushort u[8] = {f2bf(v0.x), f2bf(v0.y), f2bf(v0.z), f2bf(v0.w),
                   f2bf(v1.x), f2bf(v1.y), f2bf(v1.z), f2bf(v1.w)};
    *(uint4*)(abf + i) = *(const uint4*)u;
  } else if (bid < PREP_A2BF + PREP_WT) {
    const int wb = bid - PREP_A2BF;
    const int jb = wb & 15, kb = wb >> 4;
    const int c = tid & 63, r0 = tid >> 6;
#pragma unroll
    for (int i = 0; i < 16; ++i) {
      int kl = r0 + 4 * i;
      Ts[c][kl] = Wa[(size_t)(kb * 64 + kl) * UU + jb * 64 + c];
    }
    __syncthreads();
#pragma unroll
    for (int i = 0; i < 16; ++i) {
      int jl = r0 + 4 * i;
      WaT[(size_t)(jb * 64 + jl) * UU + kb * 64 + c] = f2bf(Ts[jl][c]);
    }
  } else {
    const int db = bid - PREP_A2BF - PREP_WT;
    const int b = db >> 2, c = db & 3;
    float* hs = &Ts[0][0];
    for (int k = tid; k < DHH; k += 256) hs[k] = h[b * DHH + k];
    __syncthreads();
    const int j = c * 256 + tid;
    float acc = Whb[j];
#pragma unroll 8
    for (int k = 0; k < DHH; ++k) acc = fmaf(hs[k], Whw[(size_t)k * UU + j], acc);
    dec[b * UU + j] = acc;
  }
}

// Standalone copies for the ws-constrained fallback path.
__global__ __launch_bounds__(256) void watrans_kernel(
    const float* __restrict__ Wa, ushort* __restrict__ WaT) {
  __shared__ float Ts[64][65];
  const int jb = blockIdx.x & 15, kb = blockIdx.x >> 4;
  const int c = threadIdx.x & 63, r0 = threadIdx.x >> 6;
#pragma unroll
  for (int i = 0; i < 16; ++i) {
    int kl = r0 + 4 * i;
    Ts[c][kl] = Wa[(size_t)(kb * 64 + kl) * UU + jb * 64 + c];
  }
  __syncthreads();
#pragma unroll
  for (int i = 0; i < 16; ++i) {
    int jl = r0 + 4 * i;
    WaT[(size_t)(jb * 64 + jl) * UU + kb * 64 + c] = f2bf(Ts[jl][c]);
  }
}

__global__ __launch_bounds__(256) void dec_kernel(
    const float* __restrict__ h, const float* __restrict__ Whw,
    const float* __restrict__ Whb, float* __restrict__ dec) {
  const int b = blockIdx.x >> 2, c = blockIdx.x & 3;
  __shared__ float hs[DHH];
  for (int k = threadIdx.x; k < DHH; k += 256) hs[k] = h[b * DHH + k];
  __syncthreads();
  const int j = c * 256 + threadIdx.x;
  float acc = Whb[j];
#pragma unroll 8
  for (int k = 0; k < DHH; ++k) acc = fmaf(hs[k], Whw[(size_t)k * UU + j], acc);
  dec[b * UU + j] = acc;
}

// ---------------------------------------------------------------------------
// K2 (round-8 proven, 198 us / MfmaUtil 29%): 256x256 tile, BK=64, 8 waves
// (2x4). LDS per operand: 2 slots x [kf(2)][frag(16)][kh(4)][i15(16)] x 16B.
// Frag-major => ds_read_b128 conflict-free; global_load_lds dest linear.
// Stages issued BEFORE the adjacent barrier (issue overlaps barrier wait —
// r13 measured stage-after-barrier costs +25%). vmcnt(6) gates per r8 ledger.
// ---------------------------------------------------------------------------
__global__ __launch_bounds__(512, 1) void e_mfma8_kernel(
    const ushort* __restrict__ abf, const ushort* __restrict__ WaT,
    const float* __restrict__ dec, const float* __restrict__ cov,
    const float* __restrict__ Wc, const float* __restrict__ v,
    const int* __restrict__ use_cov_p, float* __restrict__ partial) {
  __shared__ __align__(16) ushort aS[32768];  // 2 slots x 32 KB
  __shared__ __align__(16) ushort bS[32768];  // 2 slots x 32 KB
  __shared__ float dec_s[256], v_s[256], wc_s[256], cov_s[256];
  __shared__ float peL[4][256];

  const int tid = threadIdx.x;
  const int lane = tid & 63;
  const int w = tid >> 6;            // 0..7
  const int wm = w >> 2, wn = w & 3; // 2 x 4 waves

  // XCD swizzle: 4 consecutive blocks within an XCD = 4 nt of one mt.
  const int x = blockIdx.x & 7;
  const int r = blockIdx.x >> 3;     // 0..127
  const int nt = r & 3;
  const int mt = (r >> 2) * 8 + x;   // 0..255

  const int j0 = nt * 256;
  const int row0 = mt * 256;
  const int b = row0 >> 11;
  const int trow0 = row0 & (TXX - 1);

  if (tid < 256) {
    dec_s[tid] = dec[b * UU + j0 + tid];
    v_s[tid] = v[j0 + tid];
    wc_s[tid] = Wc[j0 + tid];
    cov_s[tid] = (*use_cov_p) ? cov[b * TXX + trow0 + tid] : 0.0f;
  }

  f4v acc[8][4];
#pragma unroll
  for (int mi = 0; mi < 8; ++mi)
#pragma unroll
    for (int ni = 0; ni < 4; ++ni) acc[mi][ni] = (f4v){0.f, 0.f, 0.f, 0.f};

  const ushort* __restrict__ aT = abf + (size_t)row0 * UU;
  const ushort* __restrict__ bT = WaT + (size_t)j0 * UU;
  const int i15 = lane & 15, khl = lane >> 4;

  auto stageA = [&](int kt, int ns, int kf) {
#pragma unroll
    for (int l = 0; l < 2; ++l) {
      const int frag = l * 8 + w;
      GLDS16(aT + (size_t)(frag * 16 + i15) * UU + kt * 64 + kf * 32 + khl * 8,
             &aS[ns * 16384 + kf * 8192 + (l * 512 + w * 64) * 8]);
    }
  };
  auto stageB = [&](int kt, int ns, int kf) {
#pragma unroll
    for (int l = 0; l < 2; ++l) {
      const int frag = l * 8 + w;
      GLDS16(bT + (size_t)(frag * 16 + i15) * UU + kt * 64 + kf * 32 + khl * 8,
             &bS[ns * 16384 + kf * 8192 + (l * 512 + w * 64) * 8]);
    }
  };
  auto readA = [&](s8v af[4], int slot, int kf, int mh) {
#pragma unroll
    for (int q = 0; q < 4; ++q) {
      const int frag = wm * 8 + mh * 4 + q;
      af[q] = *(const s8v*)&aS[slot * 16384 + kf * 8192 + frag * 512 + lane * 8];
    }
  };
  auto readB = [&](s8v bf[4], int slot, int kf) {
#pragma unroll
    for (int q = 0; q < 4; ++q) {
      const int frag = wn * 4 + q;
      bf[q] = *(const s8v*)&bS[slot * 16384 + kf * 8192 + frag * 512 + lane * 8];
    }
  };

#define MFMA16(MH)                                                          \
  do {                                                                      \
    __builtin_amdgcn_s_setprio(1);                                          \
    _Pragma("unroll")                                                       \
    for (int q = 0; q < 4; ++q)                                             \
      _Pragma("unroll")                                                     \
      for (int ni = 0; ni < 4; ++ni)                                        \
        acc[(MH)*4 + q][ni] = __builtin_amdgcn_mfma_f32_16x16x32_bf16(      \
            af[q], bf[ni], acc[(MH)*4 + q][ni], 0, 0, 0);                   \
    __builtin_amdgcn_s_setprio(0);                                          \
  } while (0)

#define VMBAR(N)                                                            \
  asm volatile("s_waitcnt vmcnt(" #N ")" ::: "memory");                     \
  __builtin_amdgcn_s_barrier();                                             \
  __builtin_amdgcn_sched_barrier(0)

  // prologue: tile 0 -> slot 0, in read order
  stageA(0, 0, 0); stageB(0, 0, 0); stageA(0, 0, 1); stageB(0, 0, 1);

  for (int t = 0; t < 16; ++t) {
    const int slot = t & 1, ns = slot ^ 1;
    s8v af[4], bf[4];
    // p0: MFMA (mi 0-3) x kf0
    if (t < 15) { stageA(t + 1, ns, 0); VMBAR(6); } else { VMBAR(4); }
    readB(bf, slot, 0);
    readA(af, slot, 0, 0);
    MFMA16(0);
    // p1: MFMA (mi 4-7) x kf0  (B regs reused)
    if (t < 15) stageB(t + 1, ns, 0);
    readA(af, slot, 0, 1);
    MFMA16(1);
    // p2: MFMA (mi 0-3) x kf1
    if (t < 15) { stageA(t + 1, ns, 1); VMBAR(6); } else { VMBAR(0); }
    readB(bf, slot, 1);
    readA(af, slot, 1, 0);
    MFMA16(0);
    // p3: MFMA (mi 4-7) x kf1
    if (t < 15) stageB(t + 1, ns, 1);
    readA(af, slot, 1, 1);
    MFMA16(1);
  }
#undef VMBAR
#undef MFMA16

  // epilogue: f = acc + dec[j] + cov[m]*Wc[j]; pe += v[j]*tanh(f);
  // C/D map (m89/m91): col = lane&15, row = (lane>>4)*4 + reg.
  const int lj = lane & 15, lk = lane >> 4;
#pragma unroll
  for (int mi = 0; mi < 8; ++mi) {
#pragma unroll
    for (int r2 = 0; r2 < 4; ++r2) {
      const int rowl = wm * 128 + mi * 16 + lk * 4 + r2;
      const float cv = cov_s[rowl];
      float s = 0.f;
#pragma unroll
      for (int ni = 0; ni < 4; ++ni) {
        const int jl = wn * 64 + ni * 16 + lj;
        float f = acc[mi][ni][r2] + dec_s[jl] + cv * wc_s[jl];
        s += v_s[jl] * tanh_fast(f);
      }
      s += __shfl_xor(s, 1); s += __shfl_xor(s, 2);
      s += __shfl_xor(s, 4); s += __shfl_xor(s, 8);
      if (lj == 0) peL[wn][rowl] = s;
    }
  }
  __syncthreads();
  if (tid < 256)
    partial[(size_t)nt * MM + row0 + tid] =
        peL[0][tid] + peL[1][tid] + peL[2][tid] + peL[3][tid];
}

// ---------------------------------------------------------------------------
// K2 slow (fallback if ws too small): reg-staging kernel (round-3 proven).
// ---------------------------------------------------------------------------
__device__ __forceinline__ void e_epilogue8(
    f4v acc[4][4], const float* dec_s, const float* v_s, const float* wc_s,
    const float* cov_s, float peL[2][128], int lane, int wm, int wn,
    float* __restrict__ partial, int nt, int row0, int tid) {
  const int lj = lane & 15, lk = lane >> 4;
#pragma unroll
  for (int mi = 0; mi < 4; ++mi) {
#pragma unroll
    for (int r = 0; r < 4; ++r) {
      const int rowl = (wm << 6) + (mi << 4) + (lk << 2) + r;
      const float cv = cov_s[rowl];
      float s = 0.f;
#pragma unroll
      for (int ni = 0; ni < 4; ++ni) {
        const int jl = (wn << 6) + (ni << 4) + lj;
        float f = acc[mi][ni][r] + dec_s[jl] + cv * wc_s[jl];
        s += v_s[jl] * tanh_fast(f);
      }
      s += __shfl_xor(s, 1); s += __shfl_xor(s, 2);
      s += __shfl_xor(s, 4); s += __shfl_xor(s, 8);
      if (lj == 0) peL[wn][rowl] = s;
    }
  }
  __syncthreads();
  if (tid < 128)
    partial[(size_t)nt * MM + row0 + tid] = peL[0][tid] + peL[1][tid];
}

__global__ __launch_bounds__(256) void e_mfma_slow_kernel(
    const float* __restrict__ a, const ushort* __restrict__ WaT,
    const float* __restrict__ dec, const float* __restrict__ cov,
    const float* __restrict__ Wc, const float* __restrict__ v,
    const int* __restrict__ use_cov_p, float* __restrict__ partial) {
  __shared__ __align__(16) ushort aS[4096];
  __shared__ __align__(16) ushort bS[4096];
  __shared__ float dec_s[128], v_s[128], wc_s[128], cov_s[128];
  __shared__ float peL[2][128];

  const int tid = threadIdx.x;
  const int lane = tid & 63;
  const int wid = tid >> 6;
  const int wm = wid >> 1, wn = wid & 1;

  const int x = blockIdx.x & 7;
  const int q = blockIdx.x >> 3;
  const int nt = q & 7;
  const int mt = (q >> 3) * 8 + x;

  const int j0 = nt * 128;
  const int row0 = mt * 128;
  const int b = row0 >> 11;
  const int trow0 = row0 & (TXX - 1);

  if (tid < 128) {
    dec_s[tid] = dec[b * UU + j0 + tid];
    v_s[tid] = v[j0 + tid];
    wc_s[tid] = Wc[j0 + tid];
    cov_s[tid] = (*use_cov_p) ? cov[b * TXX + trow0 + tid] : 0.0f;
  }

  f4v zero = {0.f, 0.f, 0.f, 0.f};
  f4v acc[4][4];
#pragma unroll
  for (int mi = 0; mi < 4; ++mi)
#pragma unroll
    for (int ni = 0; ni < 4; ++ni) acc[mi][ni] = zero;

  const float* __restrict__ aRow = a + (size_t)row0 * UU;
  const int arow = tid >> 3;
  const int kq = (tid & 7) * 4;
  const int jrow = tid >> 2;
  const int kc = tid & 3;

  for (int ks = 0; ks < 32; ++ks) {
    const int k0 = ks * 32;
#pragma unroll
    for (int l = 0; l < 4; ++l) {
      const int row = l * 32 + arow;
      float4 va = *(const float4*)(aRow + (size_t)row * UU + k0 + kq);
      ushort4 ub = make_ushort4(f2bf(va.x), f2bf(va.y), f2bf(va.z), f2bf(va.w));
      const int unit = ldsu(row >> 4, kq >> 3, row & 15);
      *(ushort4*)&aS[unit * 8 + (kq & 7)] = ub;
    }
#pragma unroll
    for (int l = 0; l < 2; ++l) {
      const int jr = l * 64 + jrow;
      uint4 wv = *(const uint4*)(WaT + (size_t)(j0 + jr) * UU + k0 + kc * 8);
      *(uint4*)&bS[ldsu(jr >> 4, kc, jr & 15) * 8] = wv;
    }
    __syncthreads();
    s8v af[4], bff[4];
    const int kh = lane >> 4, i15 = lane & 15;
#pragma unroll
    for (int mi = 0; mi < 4; ++mi)
      af[mi] = *(const s8v*)&aS[ldsu((wm << 2) + mi, kh, i15) * 8];
#pragma unroll
    for (int ni = 0; ni < 4; ++ni)
      bff[ni] = *(const s8v*)&bS[ldsu((wn << 2) + ni, kh, i15) * 8];
#pragma unroll
    for (int mi = 0; mi < 4; ++mi)
#pragma unroll
      for (int ni = 0; ni < 4; ++ni)
        acc[mi][ni] = __builtin_amdgcn_mfma_f32_16x16x32_bf16(af[mi], bff[ni], acc[mi][ni], 0, 0, 0);
    __syncthreads();
  }

  e_epilogue8(acc, dec_s, v_s, wc_s, cov_s, peL, lane, wm, wn, partial, nt, row0, tid);
}

// ---------------------------------------------------------------------------
// K3: e = sum of npart partials; masked softmax over TX.
// ---------------------------------------------------------------------------
__global__ __launch_bounds__(256) void softmax_kernel(
    const float* __restrict__ partial, const void* __restrict__ mask,
    const int* __restrict__ use_mask_p, float* __restrict__ alpha, int npart) {
  int b = blockIdx.x;
  int tid = threadIdx.x;
  int lane = tid & 63, wv = tid >> 6;
  const unsigned char* m8 = (const unsigned char*)mask;
  const int* m32 = (const int*)mask;
  int um = *use_mask_p;

  __shared__ int isBoolS;
  if (tid == 0) isBoolS = 0;

  __shared__ float es[TXX];
  for (int t = tid; t < TXX; t += 256) {
    float s = 0.f;
    for (int nt = 0; nt < npart; ++nt) s += partial[(size_t)nt * MM + b * TXX + t];
    es[t] = s;
  }
  __syncthreads();
  {
    // int32-encoded 0/1 masks have all bytes at (i%4 != 0) == 0.
    uint4 qq = ((const uint4*)mask)[tid];
    unsigned nz = (qq.x | qq.y | qq.z | qq.w) & 0xFFFFFF00u;
    if (nz) atomicOr(&isBoolS, 1);
  }
  __syncthreads();
  const int isBool = isBoolS;

  float m = -1e30f;
  for (int t = tid; t < TXX; t += 256) m = fmaxf(m, es[t]);
#pragma unroll
  for (int o = 32; o > 0; o >>= 1) m = fmaxf(m, __shfl_xor(m, o, 64));
  __shared__ float redm[4];
  if (lane == 0) redm[wv] = m;
  __syncthreads();
  m = fmaxf(fmaxf(redm[0], redm[1]), fmaxf(redm[2], redm[3]));

  float s = 0.f;
  for (int t = tid; t < TXX; t += 256) {
    float w = __expf(es[t] - m);
    if (um) {
      int mv = isBool ? (int)m8[b * TXX + t] : m32[b * TXX + t];
      if (mv == 0) w = 0.f;
    }
    s += w;
  }
#pragma unroll
  for (int o = 32; o > 0; o >>= 1) s += __shfl_xor(s, o, 64);
  __shared__ float reds[4];
  if (lane == 0) reds[wv] = s;
  __syncthreads();
  s = reds[0] + reds[1] + reds[2] + reds[3];
  float inv = 1.0f / s;

  for (int t = tid; t < TXX; t += 256) {
    float w = __expf(es[t] - m);
    if (um) {
      int mv = isBool ? (int)m8[b * TXX + t] : m32[b * TXX + t];
      if (mv == 0) w = 0.f;
    }
    alpha[b * TXX + t] = w * inv;
  }
}

// ---------------------------------------------------------------------------
// K4 (bf16 input): cpart[ts][b][d] = sum_{t in chunk} alpha[b,t]*abf[b,t,d]
// ---------------------------------------------------------------------------
__global__ __launch_bounds__(256) void context_bf_kernel(
    const ushort* __restrict__ abf, const float* __restrict__ alpha,
    float* __restrict__ cpart) {
  const int b = blockIdx.x >> 4;
  const int ts = blockIdx.x & 15;
  const int th = threadIdx.x >> 7;
  const int c = threadIdx.x & 127;
  const int dc = c * 8;
  const ushort* __restrict__ ab = abf + (size_t)(b * TXX + ts * 128) * UU + dc;
  const float* __restrict__ alb = alpha + b * TXX + ts * 128;
  float acc[8] = {0.f, 0.f, 0.f, 0.f, 0.f, 0.f, 0.f, 0.f};
  for (int t = th; t < 128; t += 2) {
    float al = alb[t];
    union { uint4 q; ushort us[8]; } Q;
    Q.q = *(const uint4*)(ab + (size_t)t * UU);
#pragma unroll
    for (int u = 0; u < 8; ++u) acc[u] = fmaf(al, bf2f(Q.us[u]), acc[u]);
  }
  __shared__ float s2[2][128][8];
#pragma unroll
  for (int u = 0; u < 8; ++u) s2[th][c][u] = acc[u];
  __syncthreads();
  if (th == 0) {
    float o[8];
#pragma unroll
    for (int u = 0; u < 8; ++u) o[u] = s2[0][c][u] + s2[1][c][u];
    float* dst = cpart + (size_t)(ts * BB + b) * UU + dc;
    *(float4*)dst = make_float4(o[0], o[1], o[2], o[3]);
    *(float4*)(dst + 4) = make_float4(o[4], o[5], o[6], o[7]);
  }
}

// K4 fallback (f32 input), round-3 proven.
__global__ __launch_bounds__(256) void context_f32_kernel(
    const float* __restrict__ a, const float* __restrict__ alpha,
    float* __restrict__ cpart) {
  const int b = blockIdx.x >> 4;
  const int ts = blockIdx.x & 15;
  const int d4 = threadIdx.x * 4;
  const float* __restrict__ ab  = a + (size_t)(b * TXX + ts * 128) * UU;
  const float* __restrict__ alb = alpha + b * TXX + ts * 128;
  float4 acc = {0.f, 0.f, 0.f, 0.f};
  for (int t = 0; t < 128; t += 4) {
#pragma unroll
    for (int u = 0; u < 4; ++u) {
      float al = alb[t + u];
      float4 va = *(const float4*)(ab + (size_t)(t + u) * UU + d4);
      acc.x = fmaf(al, va.x, acc.x);
      acc.y = fmaf(al, va.y, acc.y);
      acc.z = fmaf(al, va.z, acc.z);
      acc.w = fmaf(al, va.w, acc.w);
    }
  }
  *(float4*)(cpart + (size_t)(ts * BB + b) * UU + d4) = acc;
}

// K5: ctx[b][d] = sum_ts cpart[ts][b][d]
__global__ __launch_bounds__(256) void ctx_reduce_kernel(
    const float* __restrict__ cpart, float* __restrict__ ctx) {
  int i = blockIdx.x * 256 + threadIdx.x;
  float s = 0.f;
#pragma unroll
  for (int ts = 0; ts < 16; ++ts) s += cpart[(size_t)ts * BB * UU + i];
  ctx[i] = s;
}

// ---------------------------------------------------------------------------
extern "C" void kernel_launch(void* const* d_in, const int* in_sizes, int n_in,
                              void* d_out, int out_size, void* d_ws, size_t ws_size,
                              hipStream_t stream) {
  const float* a   = (const float*)d_in[0];
  const float* h   = (const float*)d_in[1];
  const float* cov = (const float*)d_in[2];
  const void*  msk = d_in[3];
  const float* Wa  = (const float*)d_in[4];
  const float* Whw = (const float*)d_in[5];
  const float* Whb = (const float*)d_in[6];
  const float* Wc  = (const float*)d_in[7];
  const float* v   = (const float*)d_in[8];
  const int* use_cov  = (const int*)d_in[9];
  const int* use_mask = (const int*)d_in[10];

  float*  dec     = (float*)d_ws;                                  // 128 KB
  ushort* WaT     = (ushort*)((char*)d_ws + 131072);               // 2 MB
  float*  partial = (float*)((char*)d_ws + 131072 + 2097152);      // 2 MB
  float*  cpart   = partial;  // reuse: softmax consumes partial before K4
  ushort* abf     = (ushort*)((char*)d_ws + 4325376);              // 128 MB
  const size_t need = 4325376 + (size_t)MM * UU * 2;

  float* ctx   = (float*)d_out;
  float* alpha = (float*)d_out + BB * UU;

  if (ws_size >= need) {
    prep_kernel<<<PREP_GRID, 256, 0, stream>>>(a, abf, Wa, WaT, h, Whw, Whb, dec);
    e_mfma8_kernel<<<(MM / 256) * 4, 512, 0, stream>>>(abf, WaT, dec, cov, Wc, v, use_cov, partial);
    softmax_kernel<<<BB, 256, 0, stream>>>(partial, msk, use_mask, alpha, 4);
    context_bf_kernel<<<BB * 16, 256, 0, stream>>>(abf, alpha, cpart);
  } else {
    watrans_kernel<<<256, 256, 0, stream>>>(Wa, WaT);
    dec_kernel<<<BB * 4, 256, 0, stream>>>(h, Whw, Whb, dec);
    e_mfma_slow_kernel<<<(MM / 128) * 8, 256, 0, stream>>>(a, WaT, dec, cov, Wc, v, use_cov, partial);
    softmax_kernel<<<BB, 256, 0, stream>>>(partial, msk, use_mask, alpha, 8);
    context_f32_kernel<<<BB * 16, 256, 0, stream>>>(a, alpha, cpart);
  }
  ctx_reduce_kernel<<<BB * UU / 256, 256, 0, stream>>>(cpart, ctx);
}